// Round 14
// baseline (509.059 us; speedup 1.0000x reference)
//
#include <hip/hip_runtime.h>
#include <hip/hip_bf16.h>
#include <math.h>

#define DIMX 1536
#define SEQ 2048
#define L2X 512
#define NHEAD 12
#define HDIM 128
#define NBLK 32
#define FFNX 8960
#define SCALE_ATT 0.08838834764831845f

typedef __attribute__((ext_vector_type(4))) float f4;
typedef __attribute__((ext_vector_type(4))) float f32x4;
typedef __attribute__((ext_vector_type(8))) short bf16x8;
typedef __attribute__((ext_vector_type(4))) unsigned short us4;
typedef __attribute__((ext_vector_type(8))) unsigned short us8;
typedef unsigned short us;

static __device__ __forceinline__ us f2bf(float f) {
  union { float f; unsigned u; } v; v.f = f;
  unsigned r = v.u + 0x7FFFu + ((v.u >> 16) & 1u);
  return (us)(r >> 16);
}

static __device__ __forceinline__ float bf2f(us h) {
  union { unsigned u; float f; } v; v.u = ((unsigned)h) << 16;
  return v.f;
}

static __device__ __forceinline__ void gl_lds16(const us* g, us* l) {
  __builtin_amdgcn_global_load_lds(
      (const __attribute__((address_space(1))) void*)g,
      (__attribute__((address_space(3))) void*)l, 16, 0, 0);
}

#define RAW_BAR() asm volatile("s_barrier" ::: "memory")

static __device__ __forceinline__ void xcd_map2(int& bx, int& by) {
  int gx = gridDim.x, gy = gridDim.y;
  int nwg = gx * gy;
  int lin = by * gx + bx;
  int q = nwg >> 3;
  lin = (lin & 7) * q + (lin >> 3);
  bx = lin % gx;
  by = lin / gx;
}

// ---------------------------------------------------------------------------
__global__ void __launch_bounds__(256) prep_e_kernel(const float* __restrict__ sst,
                                                     const float* __restrict__ temb,
                                                     float* __restrict__ e) {
  int i = blockIdx.x * 256 + threadIdx.x;
  if (i < 6 * DIMX) e[i] = sst[i] + temb[i];
}

// ---------------------------------------------------------------------------
struct P9 { const float* s[9]; };

__global__ void __launch_bounds__(256) pack64_9(P9 ps, us* __restrict__ dst) {
  const float* __restrict__ W = ps.s[blockIdx.z];
  us* __restrict__ Wt = dst + (size_t)blockIdx.z * DIMX * DIMX;
  __shared__ float t[64][65];
  int n0 = blockIdx.x * 64, k0 = blockIdx.y * 64;
  int tid = threadIdx.x;
#pragma unroll
  for (int i = 0; i < 4; i++) {
    int c = i * 256 + tid;
    int row = c >> 4, c4 = (c & 15) * 4;
    *reinterpret_cast<f4*>(&t[row][c4]) =
        *reinterpret_cast<const f4*>(&W[(size_t)(k0 + row) * DIMX + n0 + c4]);
  }
  __syncthreads();
#pragma unroll
  for (int i = 0; i < 2; i++) {
    int c = i * 256 + tid;
    int n = c >> 3, kc = (c & 7) * 8;
    us8 h;
#pragma unroll
    for (int j = 0; j < 8; j++) h[j] = f2bf(t[kc + j][n]);
    *reinterpret_cast<us8*>(&Wt[(size_t)(n0 + n) * DIMX + k0 + kc]) = h;
  }
}

__global__ void __launch_bounds__(256) pack64_g(const float* __restrict__ W,
                                                us* __restrict__ Wt, int K, int N) {
  __shared__ float t[64][65];
  int n0 = blockIdx.x * 64, k0 = blockIdx.y * 64;
  int tid = threadIdx.x;
#pragma unroll
  for (int i = 0; i < 4; i++) {
    int c = i * 256 + tid;
    int row = c >> 4, c4 = (c & 15) * 4;
    *reinterpret_cast<f4*>(&t[row][c4]) =
        *reinterpret_cast<const f4*>(&W[(size_t)(k0 + row) * N + n0 + c4]);
  }
  __syncthreads();
#pragma unroll
  for (int i = 0; i < 2; i++) {
    int c = i * 256 + tid;
    int n = c >> 3, kc = (c & 7) * 8;
    us8 h;
#pragma unroll
    for (int j = 0; j < 8; j++) h[j] = f2bf(t[kc + j][n]);
    *reinterpret_cast<us8*>(&Wt[(size_t)(n0 + n) * K + k0 + kc]) = h;
  }
}

__global__ void __launch_bounds__(256) pack_cvt_kernel(const float* __restrict__ X,
                                                       us* __restrict__ Y, int n4) {
  int i = blockIdx.x * 256 + threadIdx.x;
  if (i < n4) {
    f4 v = *reinterpret_cast<const f4*>(&X[(size_t)i * 4]);
    us4 h; h[0] = f2bf(v[0]); h[1] = f2bf(v[1]); h[2] = f2bf(v[2]); h[3] = f2bf(v[3]);
    *reinterpret_cast<us4*>(&Y[(size_t)i * 4]) = h;
  }
}

// ---------------------------------------------------------------------------
__global__ void __launch_bounds__(256) ln_affine_kernel(
    const float* __restrict__ X, const float* __restrict__ a,
    const float* __restrict__ b, int add1, us* __restrict__ Out) {
  __shared__ float lds4[4];
  int row = blockIdx.x, t = threadIdx.x;
  const float* x = X + (size_t)row * DIMX;
  float v[6]; float s = 0.f;
#pragma unroll
  for (int i = 0; i < 6; i++) { v[i] = x[t + 256 * i]; s += v[i]; }
  for (int o = 1; o < 64; o <<= 1) s += __shfl_xor(s, o, 64);
  if ((t & 63) == 0) lds4[t >> 6] = s;
  __syncthreads();
  float mean = (lds4[0] + lds4[1] + lds4[2] + lds4[3]) * (1.f / DIMX);
  __syncthreads();
  float s2 = 0.f;
#pragma unroll
  for (int i = 0; i < 6; i++) { float c = v[i] - mean; s2 += c * c; }
  for (int o = 1; o < 64; o <<= 1) s2 += __shfl_xor(s2, o, 64);
  if ((t & 63) == 0) lds4[t >> 6] = s2;
  __syncthreads();
  float var = (lds4[0] + lds4[1] + lds4[2] + lds4[3]) * (1.f / DIMX);
  float rstd = rsqrtf(var + 1e-6f);
#pragma unroll
  for (int i = 0; i < 6; i++) {
    int c = t + 256 * i;
    float av = a[c] + (add1 ? 1.f : 0.f);
    Out[(size_t)row * DIMX + c] = f2bf((v[i] - mean) * rstd * av + b[c]);
  }
}

// ---------------------------------------------------------------------------
// fused: x = R + [g*] (P0+P1+P2+P3 + bias); Ores=x; Onorm=LN(x)*(a+add1)+b (bf16)
__global__ void __launch_bounds__(256) reduce_ln_kernel(
    const float* __restrict__ P, const float* __restrict__ bias,
    const float* __restrict__ R, const float* __restrict__ g,
    float* __restrict__ Ores, const float* __restrict__ a,
    const float* __restrict__ b, int add1, us* __restrict__ Onorm) {
  __shared__ float lds4[4];
  int row = blockIdx.x, t = threadIdx.x;
  const size_t RN = (size_t)SEQ * DIMX;
  float v[6]; float s = 0.f;
#pragma unroll
  for (int i = 0; i < 6; i++) {
    int c = t + 256 * i;
    size_t ix = (size_t)row * DIMX + c;
    float x = P[ix];
    x += P[RN + ix]; x += P[2 * RN + ix]; x += P[3 * RN + ix];
    x += bias[c];
    x = g ? (R[ix] + g[c] * x) : (R[ix] + x);
    Ores[ix] = x;
    v[i] = x; s += x;
  }
  for (int o = 1; o < 64; o <<= 1) s += __shfl_xor(s, o, 64);
  if ((t & 63) == 0) lds4[t >> 6] = s;
  __syncthreads();
  float mean = (lds4[0] + lds4[1] + lds4[2] + lds4[3]) * (1.f / DIMX);
  __syncthreads();
  float s2 = 0.f;
#pragma unroll
  for (int i = 0; i < 6; i++) { float c = v[i] - mean; s2 += c * c; }
  for (int o = 1; o < 64; o <<= 1) s2 += __shfl_xor(s2, o, 64);
  if ((t & 63) == 0) lds4[t >> 6] = s2;
  __syncthreads();
  float var = (lds4[0] + lds4[1] + lds4[2] + lds4[3]) * (1.f / DIMX);
  float rstd = rsqrtf(var + 1e-6f);
#pragma unroll
  for (int i = 0; i < 6; i++) {
    int c = t + 256 * i;
    float av = a[c] + (add1 ? 1.f : 0.f);
    Onorm[(size_t)row * DIMX + c] = f2bf((v[i] - mean) * rstd * av + b[c]);
  }
}

// ---------------------------------------------------------------------------
// fused cross-Q: x = P0+P1+P2+P3+bias; Ob = bf16(RMS(x)*w)
__global__ void __launch_bounds__(256) reduce_rms_kernel(
    const float* __restrict__ P, const float* __restrict__ bias,
    const float* __restrict__ w, us* __restrict__ Ob) {
  __shared__ float lds4[4];
  int row = blockIdx.x, t = threadIdx.x;
  const size_t RN = (size_t)SEQ * DIMX;
  float v[6]; float s2 = 0.f;
#pragma unroll
  for (int i = 0; i < 6; i++) {
    int c = t + 256 * i;
    size_t ix = (size_t)row * DIMX + c;
    float x = P[ix];
    x += P[RN + ix]; x += P[2 * RN + ix]; x += P[3 * RN + ix];
    x += bias[c];
    v[i] = x; s2 += x * x;
  }
  for (int o = 1; o < 64; o <<= 1) s2 += __shfl_xor(s2, o, 64);
  if ((t & 63) == 0) lds4[t >> 6] = s2;
  __syncthreads();
  float ms = (lds4[0] + lds4[1] + lds4[2] + lds4[3]) * (1.f / DIMX);
  float rstd = rsqrtf(ms + 1e-6f);
#pragma unroll
  for (int i = 0; i < 6; i++) {
    int c = t + 256 * i;
    float y = v[i] * (rstd * w[c]);
    Ob[(size_t)row * DIMX + c] = f2bf(y);
  }
}

// ---------------------------------------------------------------------------
// fused q+k RMS(+RoPE): z=blockIdx.y selects stream; in-place f32 + bf16 mirror
__global__ void __launch_bounds__(256) rms_rope2_kernel(
    float* __restrict__ X0, float* __restrict__ X1,
    const float* __restrict__ w0, const float* __restrict__ w1,
    const float* __restrict__ cosT, const float* __restrict__ sinT, int do_rope,
    us* __restrict__ O0, us* __restrict__ O1) {
  __shared__ float lds4[4];
  int row = blockIdx.x, t = threadIdx.x;
  float* x = (blockIdx.y ? X1 : X0) + (size_t)row * DIMX;
  const float* wgt = blockIdx.y ? w1 : w0;
  us* Ob = blockIdx.y ? O1 : O0;
  int base = t * 6;
  float v[6]; float s2 = 0.f;
#pragma unroll
  for (int i = 0; i < 6; i++) { v[i] = x[base + i]; s2 += v[i] * v[i]; }
  for (int o = 1; o < 64; o <<= 1) s2 += __shfl_xor(s2, o, 64);
  if ((t & 63) == 0) lds4[t >> 6] = s2;
  __syncthreads();
  float ms = (lds4[0] + lds4[1] + lds4[2] + lds4[3]) * (1.f / DIMX);
  float rstd = rsqrtf(ms + 1e-6f);
#pragma unroll
  for (int i = 0; i < 6; i++) v[i] *= rstd * wgt[base + i];
  if (do_rope) {
#pragma unroll
    for (int j = 0; j < 3; j++) {
      int c = base + 2 * j;
      int pi = (c & (HDIM - 1)) >> 1;
      float cs = cosT[row * (HDIM / 2) + pi], sn = sinT[row * (HDIM / 2) + pi];
      float ev = v[2 * j], ov = v[2 * j + 1];
      v[2 * j] = ev * cs - ov * sn;
      v[2 * j + 1] = ov * cs + ev * sn;
    }
  }
#pragma unroll
  for (int i = 0; i < 6; i++) {
    x[base + i] = v[i];
    Ob[(size_t)row * DIMX + base + i] = f2bf(v[i]);
  }
}

// single-stream variant (cross-attn k)
__global__ void __launch_bounds__(256) rms_rope_kernel(
    float* __restrict__ X, const float* __restrict__ wgt,
    const float* __restrict__ cosT, const float* __restrict__ sinT, int do_rope,
    us* __restrict__ Ob) {
  __shared__ float lds4[4];
  int row = blockIdx.x, t = threadIdx.x;
  float* x = X + (size_t)row * DIMX;
  int base = t * 6;
  float v[6]; float s2 = 0.f;
#pragma unroll
  for (int i = 0; i < 6; i++) { v[i] = x[base + i]; s2 += v[i] * v[i]; }
  for (int o = 1; o < 64; o <<= 1) s2 += __shfl_xor(s2, o, 64);
  if ((t & 63) == 0) lds4[t >> 6] = s2;
  __syncthreads();
  float ms = (lds4[0] + lds4[1] + lds4[2] + lds4[3]) * (1.f / DIMX);
  float rstd = rsqrtf(ms + 1e-6f);
#pragma unroll
  for (int i = 0; i < 6; i++) v[i] *= rstd * wgt[base + i];
  if (do_rope) {
#pragma unroll
    for (int j = 0; j < 3; j++) {
      int c = base + 2 * j;
      int pi = (c & (HDIM - 1)) >> 1;
      float cs = cosT[row * (HDIM / 2) + pi], sn = sinT[row * (HDIM / 2) + pi];
      float ev = v[2 * j], ov = v[2 * j + 1];
      v[2 * j] = ev * cs - ov * sn;
      v[2 * j + 1] = ov * cs + ev * sn;
    }
  }
#pragma unroll
  for (int i = 0; i < 6; i++) {
    x[base + i] = v[i];
    Ob[(size_t)row * DIMX + base + i] = f2bf(v[i]);
  }
}

// ---------------------------------------------------------------------------
struct Outs {
  float *o0, *o1, *o2, *o3;
  const float *b0, *b1, *b2, *b3;
  us* ob;   // bf16 mirror for chunk 2 (V)
  us* ob2;  // bf16-only output for chunk 3 (G)
};

// ===========================================================================
// gemm2ph: 8-wave (4M x 2N) 256 x (NP*32) tile, BK=64, 2 phases/K-tile,
// counted vmcnt tail-pinning.
// ===========================================================================
template<int NP, int NCHUNK, int OUT_BF16, int DO_GELU, int SPLITK, int DIRECT>
__global__ void __launch_bounds__(512, 2) gemm2ph(
    const us* __restrict__ A, const us* __restrict__ Bt,
    Outs outs, int M, int N, int K, int Kfull) {
  constexpr int NT = NP * 32;
  constexpr int TOT = 16384 + NT * 64;
  constexpr int BI = (NT * 8 + 511) / 512;
  constexpr int NH0 = NP / 2;
  constexpr int NH1 = NP - NH0;
  __shared__ __align__(16) us S[2 * TOT];
  const int tid = threadIdx.x;
  const int lane = tid & 63;
  const int wid = tid >> 6;
  const int wr = wid >> 1, wc = wid & 1;
  const int fr = lane & 15, xo = lane >> 4;
  const int r7 = fr & 7, q4 = xo * 4;
  int tm, tn;
  if (DIRECT) {
    tm = blockIdx.x * 256; tn = blockIdx.y * NT;
  } else {
    int bx = blockIdx.x, by = blockIdx.y;
    xcd_map2(bx, by);
    tm = by * 256; tn = bx * NT;
  }
  const size_t kb = SPLITK ? (size_t)blockIdx.z * K : 0;

  auto stA = [&](int buf, int k0) {
#pragma unroll
    for (int i = 0; i < 4; i++) {
      int c = i * 512 + tid;
      gl_lds16(A + (size_t)(tm + (c >> 3)) * Kfull + kb + k0 + (((c & 7) ^ ((c >> 3) & 7)) * 8),
               S + buf * TOT + (i * 512 + wid * 64) * 8);
    }
  };
  auto stB = [&](int buf, int k0) {
#pragma unroll
    for (int i = 0; i < BI; i++) {
      int c = i * 512 + tid;
      if (c < NT * 8)
        gl_lds16(Bt + (size_t)(tn + (c >> 3)) * Kfull + kb + k0 + (((c & 7) ^ ((c >> 3) & 7)) * 8),
                 S + buf * TOT + 16384 + (i * 512 + wid * 64) * 8);
    }
  };
  auto rdA = [&](int buf, int mp, int ks) -> bf16x8 {
    int r = wr * 64 + mp * 16 + fr;
    int ko = ((ks * 4 + xo) ^ r7) * 8;
    return *reinterpret_cast<const bf16x8*>(&S[buf * TOT + r * 64 + ko]);
  };
  auto rdB = [&](int buf, int np, int ks) -> bf16x8 {
    int r = wc * (NP * 16) + np * 16 + fr;
    int ko = ((ks * 4 + xo) ^ r7) * 8;
    return *reinterpret_cast<const bf16x8*>(&S[buf * TOT + 16384 + r * 64 + ko]);
  };

  f32x4 acc[4][NP];
#pragma unroll
  for (int m = 0; m < 4; m++)
#pragma unroll
    for (int n = 0; n < NP; n++) acc[m][n] = (f32x4)(0.f);
  bf16x8 aF[2][4], bFr[2][NH1 > NH0 ? NH1 : NH0];

  const int nt = K >> 6;
  stA(0, 0); stB(0, 0); stA(1, 64);
  asm volatile("s_waitcnt vmcnt(4)" ::: "memory");
  RAW_BAR();

  for (int t = 0; t < nt; t++) {
    const int buf = t & 1;
    const int k1 = (t + 1) << 6, k2 = (t + 2) << 6;
#pragma unroll
    for (int ks = 0; ks < 2; ks++)
#pragma unroll
      for (int m = 0; m < 4; m++) aF[ks][m] = rdA(buf, m, ks);
#pragma unroll
    for (int ks = 0; ks < 2; ks++)
#pragma unroll
      for (int n = 0; n < NH0; n++) bFr[ks][n] = rdB(buf, n, ks);
    if (t + 1 < nt) stB(buf ^ 1, k1);
    RAW_BAR();
    __builtin_amdgcn_s_setprio(1);
#pragma unroll
    for (int ks = 0; ks < 2; ks++)
#pragma unroll
      for (int m = 0; m < 4; m++)
#pragma unroll
        for (int n = 0; n < NH0; n++)
          acc[m][n] = __builtin_amdgcn_mfma_f32_16x16x32_bf16(aF[ks][m], bFr[ks][n], acc[m][n], 0, 0, 0);
    __builtin_amdgcn_s_setprio(0);
    RAW_BAR();
#pragma unroll
    for (int ks = 0; ks < 2; ks++)
#pragma unroll
      for (int n = 0; n < NH1; n++) bFr[ks][n] = rdB(buf, NH0 + n, ks);
    if (t + 2 < nt) stA(buf, k2);
    RAW_BAR();
    __builtin_amdgcn_s_setprio(1);
#pragma unroll
    for (int ks = 0; ks < 2; ks++)
#pragma unroll
      for (int m = 0; m < 4; m++)
#pragma unroll
        for (int n = 0; n < NH1; n++)
          acc[m][NH0 + n] = __builtin_amdgcn_mfma_f32_16x16x32_bf16(aF[ks][m], bFr[ks][n], acc[m][NH0 + n], 0, 0, 0);
    __builtin_amdgcn_s_setprio(0);
    if (t + 2 < nt) asm volatile("s_waitcnt vmcnt(4)" ::: "memory");
    else            asm volatile("s_waitcnt vmcnt(0)" ::: "memory");
    RAW_BAR();
  }

#pragma unroll
  for (int m = 0; m < 4; m++)
#pragma unroll
    for (int n = 0; n < NP; n++) {
      int col = tn + wc * (NP * 16) + n * 16 + fr;
      int rowb = tm + wr * 64 + m * 16 + q4;
      if (SPLITK) {
        float* P = outs.o0 + (size_t)blockIdx.z * M * N;
#pragma unroll
        for (int r = 0; r < 4; r++)
          P[(size_t)(rowb + r) * N + col] = acc[m][n][r];
      } else {
        int c2; float* op; const float* bp; int sel = 0;
        if constexpr (NCHUNK == 1) {
          c2 = col; op = outs.o0; bp = outs.b0;
        } else {
          sel = col >= 3 * DIMX ? 3 : (col >= 2 * DIMX ? 2 : (col >= DIMX ? 1 : 0));
          c2 = col - sel * DIMX;
          op = sel == 0 ? outs.o0 : (sel == 1 ? outs.o1 : (sel == 2 ? outs.o2 : outs.o3));
          bp = sel == 0 ? outs.b0 : (sel == 1 ? outs.b1 : (sel == 2 ? outs.b2 : outs.b3));
        }
        float bv = bp[c2];
#pragma unroll
        for (int r = 0; r < 4; r++) {
          float v = acc[m][n][r] + bv;
          if (DO_GELU) {
            float u = 1.5957691216057308f * (v + 0.044715f * v * v * v);
            v = v / (1.f + __expf(-u));
          }
          if (OUT_BF16)
            outs.ob[(size_t)(rowb + r) * N + col] = f2bf(v);
          else if (NCHUNK == 4 && outs.ob2 != nullptr && sel == 3) {
            outs.ob2[(size_t)(rowb + r) * DIMX + c2] = f2bf(v);  // G: bf16 only
          } else {
            op[(size_t)(rowb + r) * DIMX + c2] = v;
            if (NCHUNK == 4 && outs.ob != nullptr && sel == 2)
              outs.ob[(size_t)(rowb + r) * DIMX + c2] = f2bf(v);
          }
        }
      }
    }
}

// ===========================================================================
// gemm10: FFN1 — 256x320 tile, 2M x 4N waves, sequential-ks 2-phase.
// ===========================================================================
__global__ void __launch_bounds__(512, 2) gemm10(
    const us* __restrict__ A, const us* __restrict__ Bt,
    const float* __restrict__ bias, us* __restrict__ Cb,
    int M, int N, int K) {
  constexpr int NT = 320;
  constexpr int TOT = 16384 + NT * 64;
  __shared__ __align__(16) us S[2 * TOT];
  const int tid = threadIdx.x;
  const int lane = tid & 63;
  const int wid = tid >> 6;
  const int wr = wid >> 2, wc = wid & 3;
  const int fr = lane & 15, xo = lane >> 4;
  const int r7 = fr & 7, q4 = xo * 4;
  const int tm = blockIdx.x * 256, tn = blockIdx.y * NT;

  auto stA = [&](int buf, int k0) {
#pragma unroll
    for (int i = 0; i < 4; i++) {
      int c = i * 512 + tid;
      gl_lds16(A + (size_t)(tm + (c >> 3)) * K + k0 + (((c & 7) ^ ((c >> 3) & 7)) * 8),
               S + buf * TOT + (i * 512 + wid * 64) * 8);
    }
  };
  auto stB = [&](int buf, int k0) {
#pragma unroll
    for (int i = 0; i < 5; i++) {
      int c = i * 512 + tid;
      gl_lds16(Bt + (size_t)(tn + (c >> 3)) * K + k0 + (((c & 7) ^ ((c >> 3) & 7)) * 8),
               S + buf * TOT + 16384 + (i * 512 + wid * 64) * 8);
    }
  };
  auto rdA = [&](int buf, int mp, int ks) -> bf16x8 {
    int r = wr * 128 + mp * 16 + fr;
    int ko = ((ks * 4 + xo) ^ r7) * 8;
    return *reinterpret_cast<const bf16x8*>(&S[buf * TOT + r * 64 + ko]);
  };
  auto rdB = [&](int buf, int np, int ks) -> bf16x8 {
    int r = wc * 80 + np * 16 + fr;
    int ko = ((ks * 4 + xo) ^ r7) * 8;
    return *reinterpret_cast<const bf16x8*>(&S[buf * TOT + 16384 + r * 64 + ko]);
  };

  f32x4 acc[8][5];
#pragma unroll
  for (int m = 0; m < 8; m++)
#pragma unroll
    for (int n = 0; n < 5; n++) acc[m][n] = (f32x4)(0.f);
  bf16x8 aF[8], bF[5];

  const int nt = K >> 6;
  stA(0, 0); stB(0, 0); stA(1, 64);
  asm volatile("s_waitcnt vmcnt(4)" ::: "memory");
  RAW_BAR();

  for (int t = 0; t < nt; t++) {
    const int buf = t & 1;
    const int k1 = (t + 1) << 6, k2 = (t + 2) << 6;
#pragma unroll
    for (int m = 0; m < 8; m++) aF[m] = rdA(buf, m, 0);
#pragma unroll
    for (int n = 0; n < 5; n++) bF[n] = rdB(buf, n, 0);
    if (t + 1 < nt) stB(buf ^ 1, k1);
    RAW_BAR();
    __builtin_amdgcn_s_setprio(1);
#pragma unroll
    for (int m = 0; m < 8; m++)
#pragma unroll
      for (int n = 0; n < 5; n++)
        acc[m][n] = __builtin_amdgcn_mfma_f32_16x16x32_bf16(aF[m], bF[n], acc[m][n], 0, 0, 0);
    __builtin_amdgcn_s_setprio(0);
    RAW_BAR();
#pragma unroll
    for (int m = 0; m < 8; m++) aF[m] = rdA(buf, m, 1);
#pragma unroll
    for (int n = 0; n < 5; n++) bF[n] = rdB(buf, n, 1);
    if (t + 2 < nt) stA(buf, k2);
    RAW_BAR();
    __builtin_amdgcn_s_setprio(1);
#pragma unroll
    for (int m = 0; m < 8; m++)
#pragma unroll
      for (int n = 0; n < 5; n++)
        acc[m][n] = __builtin_amdgcn_mfma_f32_16x16x32_bf16(aF[m], bF[n], acc[m][n], 0, 0, 0);
    __builtin_amdgcn_s_setprio(0);
    if (t + 2 < nt) asm volatile("s_waitcnt vmcnt(4)" ::: "memory");
    else            asm volatile("s_waitcnt vmcnt(0)" ::: "memory");
    RAW_BAR();
  }

#pragma unroll
  for (int m = 0; m < 8; m++)
#pragma unroll
    for (int n = 0; n < 5; n++) {
      int col = tn + wc * 80 + n * 16 + fr;
      int rowb = tm + wr * 128 + m * 16 + q4;
      float bv = bias[col];
#pragma unroll
      for (int r = 0; r < 4; r++) {
        float v = acc[m][n][r] + bv;
        float u = 1.5957691216057308f * (v + 0.044715f * v * v * v);
        v = v / (1.f + __expf(-u));
        Cb[(size_t)(rowb + r) * N + col] = f2bf(v);
      }
    }
}

// ---------------------------------------------------------------------------
// 128x128 kernel for the small cross-KV GEMM; chunk 1 (V) writes bf16 to ob.
template<int NCHUNK>
__global__ void __launch_bounds__(256) gemm_multi(
    const us* __restrict__ A, const us* __restrict__ Bt,
    Outs outs, int M, int N, int K) {
  __shared__ __align__(16) us As[128 * 64];
  __shared__ __align__(16) us Bs[128 * 64];
  const int tid = threadIdx.x;
  const int lane = tid & 63;
  const int w = tid >> 6;
  const int wr = w >> 1, wc = w & 1;
  const int fr = lane & 15;
  const int xo = lane >> 4;
  const int r7 = fr & 7;
  const int q4 = xo * 4;
  int bx = blockIdx.x, by = blockIdx.y;
  xcd_map2(bx, by);
  const int tm = by * 128, tn = bx * 128;

  f32x4 acc[4][4];
#pragma unroll
  for (int m = 0; m < 4; m++)
#pragma unroll
    for (int n = 0; n < 4; n++) acc[m][n] = (f32x4)(0.f);

  int srow[4], skc[4];
#pragma unroll
  for (int j = 0; j < 4; j++) {
    int c = j * 256 + tid;
    srow[j] = c >> 3;
    skc[j] = ((c & 7) ^ ((c >> 3) & 7)) * 8;
  }

  for (int k0 = 0; k0 < K; k0 += 64) {
#pragma unroll
    for (int j = 0; j < 4; j++) {
      gl_lds16(A + (size_t)(tm + srow[j]) * K + k0 + skc[j], As + (j * 256 + w * 64) * 8);
      gl_lds16(Bt + (size_t)(tn + srow[j]) * K + k0 + skc[j], Bs + (j * 256 + w * 64) * 8);
    }
    __syncthreads();
    bf16x8 af[2][4], bfv[2][4];
#pragma unroll
    for (int ks = 0; ks < 2; ks++) {
      const int koff = (((ks * 4 + xo) ^ r7) << 3);
#pragma unroll
      for (int m = 0; m < 4; m++)
        af[ks][m] = *reinterpret_cast<const bf16x8*>(&As[(wr * 64 + m * 16 + fr) * 64 + koff]);
#pragma unroll
      for (int n = 0; n < 4; n++)
        bfv[ks][n] = *reinterpret_cast<const bf16x8*>(&Bs[(wc * 64 + n * 16 + fr) * 64 + koff]);
    }
#pragma unroll
    for (int ks = 0; ks < 2; ks++)
#pragma unroll
      for (int m = 0; m < 4; m++)
#pragma unroll
        for (int n = 0; n < 4; n++)
          acc[m][n] = __builtin_amdgcn_mfma_f32_16x16x32_bf16(af[ks][m], bfv[ks][n], acc[m][n], 0, 0, 0);
    __syncthreads();
  }
#pragma unroll
  for (int m = 0; m < 4; m++) {
#pragma unroll
    for (int n = 0; n < 4; n++) {
      int col = tn + wc * 64 + n * 16 + fr;
      int c2; float* op; const float* bp; int sel = 0;
      if constexpr (NCHUNK == 2) {
        sel = col >= DIMX;
        c2 = col - sel * DIMX;
        op = sel ? outs.o1 : outs.o0;
        bp = sel ? outs.b1 : outs.b0;
      } else {
        c2 = col; op = outs.o0; bp = outs.b0;
      }
      float bv = bp[c2];
#pragma unroll
      for (int r = 0; r < 4; r++) {
        int row = tm + wr * 64 + m * 16 + q4 + r;
        float v = acc[m][n][r] + bv;
        if (NCHUNK == 2 && outs.ob != nullptr && sel == 1)
          outs.ob[(size_t)row * DIMX + c2] = f2bf(v);
        else
          op[(size_t)row * DIMX + c2] = v;
      }
    }
  }
}

template<int S>
__global__ void __launch_bounds__(256) reduce_kernel(
    const float* __restrict__ P, const float* __restrict__ bias,
    const float* __restrict__ R, const float* __restrict__ g,
    float* __restrict__ O, int total4, int ncol4) {
  const f4* P4 = (const f4*)P;
  const f4* R4 = (const f4*)R;
  f4* O4 = (f4*)O;
  for (int i = blockIdx.x * 256 + threadIdx.x; i < total4; i += gridDim.x * 256) {
    f4 s = P4[i];
#pragma unroll
    for (int sl = 1; sl < S; sl++) s += P4[(size_t)sl * total4 + i];
    int c4 = (i % ncol4) * 4;
    s += *reinterpret_cast<const f4*>(&bias[c4]);
    if (R) {
      if (g) {
        f4 gv = *reinterpret_cast<const f4*>(&g[c4]);
        s = R4[i] + gv * s;
      } else {
        s = R4[i] + s;
      }
    }
    O4[i] = s;
  }
}

// ---------------------------------------------------------------------------
// block-sparse flash attention, wave-owns-rows + T14 async reg-staging +
// T13 defer-max. G gate is bf16.
__global__ void __launch_bounds__(256) attn_kernel(
    const us* __restrict__ Q, const us* __restrict__ Kx,
    const us* __restrict__ V, const int* __restrict__ idx,
    const us* __restrict__ G, const float* __restrict__ CB,
    us* __restrict__ Out) {
  __shared__ us k_s[64 * 136];
  __shared__ us vT_s[128 * 72];
  __shared__ us p_s[4][16 * 72];

  const int qb = blockIdx.x;
  const int h = blockIdx.y;
  const int tid = threadIdx.x;
  const int lane = tid & 63;
  const int w = tid >> 6;
  const int fr = lane & 15;
  const int xo = lane >> 4;
  const int k8 = xo * 8;
  const int q4 = xo * 4;
  const int vd = tid & 127, vth = (tid >> 7) * 32;

  bf16x8 qF[4];
#pragma unroll
  for (int kk = 0; kk < 4; kk++)
    qF[kk] = *reinterpret_cast<const bf16x8*>(
        &Q[(size_t)(qb * 64 + w * 16 + fr) * DIMX + h * HDIM + kk * 32 + k8]);

  us8 kR[4], vR[4];
  auto loadTile = [&](int blk) {
#pragma unroll
    for (int i = 0; i < 4; i++) {
      int c = i * 256 + tid;
      int row = c >> 4, d8 = (c & 15) * 8;
      kR[i] = *reinterpret_cast<const us8*>(&Kx[(size_t)(blk * 64 + row) * DIMX + h * HDIM + d8]);
    }
#pragma unroll
    for (int j = 0; j < 4; j++) {
      us8 hv;
#pragma unroll
      for (int qq = 0; qq < 8; qq++)
        hv[qq] = V[(size_t)(blk * 64 + vth + j * 8 + qq) * DIMX + h * HDIM + vd];
      vR[j] = hv;
    }
  };

  float m_[4], l_[4];
#pragma unroll
  for (int r = 0; r < 4; r++) { m_[r] = -1e30f; l_[r] = 0.f; }
  f32x4 acc[8];
#pragma unroll
  for (int n = 0; n < 8; n++) acc[n] = (f32x4)(0.f);

  {
    int blk0 = idx ? idx[(h * NBLK + qb) * 8 + 0] : 0;
    loadTile(blk0);
  }

  for (int ib = 0; ib < 8; ib++) {
    __syncthreads();
#pragma unroll
    for (int i = 0; i < 4; i++) {
      int c = i * 256 + tid;
      int row = c >> 4, d8 = (c & 15) * 8;
      *reinterpret_cast<us8*>(&k_s[row * 136 + d8]) = kR[i];
    }
#pragma unroll
    for (int j = 0; j < 4; j++)
      *reinterpret_cast<us8*>(&vT_s[vd * 72 + vth + j * 8]) = vR[j];
    __syncthreads();
    if (ib + 1 < 8) {
      int blkn = idx ? idx[(h * NBLK + qb) * 8 + ib + 1] : ib + 1;
      loadTile(blkn);
    }
    // S = Q K^T
    f32x4 accs[4];
#pragma unroll
    for (int n = 0; n < 4; n++) accs[n] = (f32x4)(0.f);
#pragma unroll
    for (int kk = 0; kk < 4; kk++)
#pragma unroll
      for (int n = 0; n < 4; n++) {
        bf16x8 kb = *reinterpret_cast<const bf16x8*>(&k_s[(n * 16 + fr) * 136 + kk * 32 + k8]);
        accs[n] = __builtin_amdgcn_mfma_f32_16x16x32_bf16(qF[kk], kb, accs[n], 0, 0, 0);
      }
#pragma unroll
    for (int n = 0; n < 4; n++)
#pragma unroll
      for (int r = 0; r < 4; r++) accs[n][r] *= SCALE_ATT;
    // T13 defer-max online softmax
    float vmax[4];
#pragma unroll
    for (int r = 0; r < 4; r++) {
      float v = fmaxf(fmaxf(accs[0][r], accs[1][r]), fmaxf(accs[2][r], accs[3][r]));
      for (int o = 1; o < 16; o <<= 1) v = fmaxf(v, __shfl_xor(v, o, 64));
      vmax[r] = v;
    }
    int need = 0;
#pragma unroll
    for (int r = 0; r < 4; r++) need |= (vmax[r] - m_[r] > 8.f) ? 1 : 0;
    if (__any(need)) {
      float al[4];
#pragma unroll
      for (int r = 0; r < 4; r++) {
        float mn = fmaxf(m_[r], vmax[r]);
        al[r] = __expf(m_[r] - mn);
        m_[r] = mn;
        l_[r] *= al[r];
      }
#pragma unroll
      for (int n = 0; n < 8; n++) {
        acc[n][0] *= al[0]; acc[n][1] *= al[1];
        acc[n][2] *= al[2]; acc[n][3] *= al[3];
      }
    }
    float ps[4] = {0.f, 0.f, 0.f, 0.f};
#pragma unroll
    for (int n = 0; n < 4; n++)
#pragma unroll
      for (int r = 0; r < 4; r++) {
        float p = __expf(accs[n][r] - m_[r]);
        p_s[w][(q4 + r) * 72 + n * 16 + fr] = f2bf(p);
        ps[r] += p;
      }
#pragma unroll
    for (int r = 0; r < 4; r++) {
      float sv = ps[r];
      for (int o = 1; o < 16; o <<= 1) sv += __shfl_xor(sv, o, 64);
      l_[r] += sv;
    }
    bf16x8 pa[2];
#pragma unroll
    for (int ks = 0; ks < 2; ks++)
      pa[ks] = *reinterpret_cast<const bf16x8*>(&p_s[w][fr * 72 + ks * 32 + k8]);
#pragma unroll
    for (int ks = 0; ks < 2; ks++)
#pragma unroll
      for (int n = 0; n < 8; n++) {
        bf16x8 vb = *reinterpret_cast<const bf16x8*>(&vT_s[(n * 16 + fr) * 72 + ks * 32 + k8]);
        acc[n] = __builtin_amdgcn_mfma_f32_16x16x32_bf16(pa[ks], vb, acc[n], 0, 0, 0);
      }
  }
#pragma unroll
  for (int n = 0; n < 8; n++)
#pragma unroll
    for (int r = 0; r < 4; r++) {
      int srow = qb * 64 + w * 16 + q4 + r;
      int d = n * 16 + fr;
      float o = acc[n][r] / l_[r];
      size_t oi = (size_t)srow * DIMX + h * HDIM + d;
      if (G) o += bf2f(G[oi]) * CB[(size_t)qb * DIMX + h * HDIM + d];
      Out[oi] = f2bf(o);
    }
}

// ---------------------------------------------------------------------------
__global__ void __launch_bounds__(128) block_mean3_kernel(const float* __restrict__ q,
                                                          const float* __restrict__ k,
                                                          const float* __restrict__ v,
                                                          float* __restrict__ qc,
                                                          float* __restrict__ kc,
                                                          float* __restrict__ vc) {
  int n = blockIdx.x, h = blockIdx.y, z = blockIdx.z, d = threadIdx.x;
  const float* X = z == 0 ? q : (z == 1 ? k : v);
  float* O = z == 0 ? qc : (z == 1 ? kc : vc);
  float s = 0.f;
  for (int t = 0; t < 64; t++) s += X[(size_t)(n * 64 + t) * DIMX + h * HDIM + d];
  O[(n * NHEAD + h) * HDIM + d] = s * (1.f / 64.f);
}

__global__ void __launch_bounds__(256) coarse_attn_kernel(const float* __restrict__ qc,
                                                          const float* __restrict__ kc,
                                                          float* __restrict__ pc,
                                                          int* __restrict__ idxout) {
  int h = blockIdx.x, t = threadIdx.x;
  __shared__ float sm[32][32];
  for (int p = t; p < 1024; p += 256) {
    int n = p >> 5, m = p & 31;
    float dot = 0.f;
    for (int d = 0; d < HDIM; d++)
      dot += qc[n * DIMX + h * HDIM + d] * kc[m * DIMX + h * HDIM + d];
    sm[n][m] = dot * SCALE_ATT;
  }
  __syncthreads();
  if (t < 32) {
    int n = t;
    float mx = -1e30f;
#pragma unroll
    for (int m = 0; m < 32; m++) mx = fmaxf(mx, sm[n][m]);
    float pv[32]; float ssum = 0.f;
#pragma unroll
    for (int m = 0; m < 32; m++) { pv[m] = __expf(sm[n][m] - mx); ssum += pv[m]; }
    float inv = 1.f / ssum;
#pragma unroll
    for (int m = 0; m < 32; m++) { pv[m] *= inv; pc[(h * 32 + n) * 32 + m] = pv[m]; }
    unsigned chosen = 0;
    for (int i = 0; i < 8; i++) {
      float best = -1.f; int bi = 0;
#pragma unroll
      for (int m = 0; m < 32; m++)
        if (!((chosen >> m) & 1u) && pv[m] > best) { best = pv[m]; bi = m; }
      chosen |= 1u << bi;
      idxout[(h * 32 + n) * 8 + i] = bi;
    }
  }
}

__global__ void __launch_bounds__(128) coarse_ctx_kernel(const float* __restrict__ pc,
                                                         const float* __restrict__ vc,
                                                         float* __restrict__ cb) {
  int n = blockIdx.x, h = blockIdx.y, d = threadIdx.x;
  float s = 0.f;
  for (int m = 0; m < 32; m++)
    s += pc[(h * 32 + n) * 32 + m] * vc[(m * NHEAD + h) * HDIM + d];
  cb[(n * NHEAD + h) * HDIM + d] = s;
}

// ---------------------------------------------------------------------------
extern "C" void kernel_launch(void* const* d_in, const int* in_sizes, int n_in,
                              void* d_out, int out_size, void* d_ws, size_t ws_size,
                              hipStream_t stream) {
  (void)in_sizes; (void)n_in; (void)out_size; (void)ws_size;
  const float* hidden = (const float*)d_in[0];
  const float* enc    = (const float*)d_in[1];
  const float* temb   = (const float*)d_in[2];
  const float* cosT   = (const float*)d_in[3];
  const float* sinT   = (const float*)d_in[4];
  const float* sst    = (const float*)d_in[5];
  const float* Wq = (const float*)d_in[6];   const float* bq = (const float*)d_in[7];
  const float* Wk = (const float*)d_in[8];   const float* bk = (const float*)d_in[9];
  const float* Wv = (const float*)d_in[10];  const float* bv = (const float*)d_in[11];
  const float* Wg = (const float*)d_in[12];  const float* bg = (const float*)d_in[13];
  const float* Wo = (const float*)d_in[14];  const float* bo = (const float*)d_in[15];
  const float* qnw = (const float*)d_in[16]; const float* knw = (const float*)d_in[17];
  const float* saw = (const float*)d_in[18]; const float* sab = (const float*)d_in[19];
  const float* cWq = (const float*)d_in[20]; const float* cbq = (const float*)d_in[21];
  const float* cWk = (const float*)d_in[22]; const float* cbk = (const float*)d_in[23];
  const float* cWv = (const float*)d_in[24]; const float* cbv = (const float*)d_in[25];
  const float* cWo = (const float*)d_in[26]; const float* cbo = (const float*)d_in[27];
  const float* cqnw = (const float*)d_in[28]; const float* cknw = (const float*)d_in[29];
  const float* W1 = (const float*)d_in[30];  const float* b1 = (const float*)d_in[31];
  const float* W2 = (const float*)d_in[32];  const float* b2 = (const float*)d_in[33];

  char* ws = (char*)d_ws;
  size_t off = 0;
  auto alloc = [&](size_t bytes) -> void* {
    void* p = ws + off;
    off += (bytes + 255) & ~(size_t)255;
    return p;
  };
  const size_t SD = (size_t)SEQ * DIMX * 4;
  const size_t SDh = (size_t)SEQ * DIMX * 2;
  const size_t WSQ = (size_t)DIMX * DIMX * 2;
  float* e     = (float*)alloc(6 * DIMX * 4);
  us* normb    = (us*)alloc(SDh);
  float* qb_   = (float*)alloc(SD);   // qb_..gb_ contiguous (split-K partial space)
  float* kb_   = (float*)alloc(SD);
  float* vb_   = (float*)alloc(SD);
  float* gb_   = (float*)alloc(SD);
  us* qbh      = (us*)alloc(SDh);
  us* kbh      = (us*)alloc(SDh);
  us* vbh      = (us*)alloc(SDh);
  us* gbh      = (us*)alloc(SDh);
  float* qc    = (float*)alloc((size_t)NBLK * DIMX * 4);
  float* kc    = (float*)alloc((size_t)NBLK * DIMX * 4);
  float* vc    = (float*)alloc((size_t)NBLK * DIMX * 4);
  float* pc    = (float*)alloc(NHEAD * 32 * 32 * 4);
  int*   idx   = (int*)alloc(NHEAD * 32 * 8 * 4);
  float* cb    = (float*)alloc((size_t)NBLK * DIMX * 4);
  us* mixb     = (us*)alloc(SDh);
  float* res   = (float*)alloc(SD);
  us* encb     = (us*)alloc((size_t)L2X * DIMX * 2);
  us* wpack    = (us*)alloc(9 * WSQ);
  us* W1t      = (us*)alloc((size_t)DIMX * FFNX * 2);
  us* W2t      = (us*)alloc((size_t)FFNX * DIMX * 2);
  // aliases (lifetimes disjoint):
  us* ffh    = (us*)qb_;
  us* crossb = mixb;
  float* part4q = qb_;
  float* part4w = (float*)wpack;
  float* outf  = (float*)d_out;
  const size_t SL = (size_t)DIMX * DIMX;
  us* Wot  = wpack + 4 * SL;
  us* cWqt = wpack + 5 * SL;
  us* cKVt = wpack + 6 * SL;
  us* cWot = wpack + 8 * SL;

  // ---- pack ----
  P9 p9; p9.s[0]=Wq; p9.s[1]=Wk; p9.s[2]=Wv; p9.s[3]=Wg; p9.s[4]=Wo;
  p9.s[5]=cWq; p9.s[6]=cWk; p9.s[7]=cWv; p9.s[8]=cWo;
  pack64_9<<<dim3(DIMX / 64, DIMX / 64, 9), 256, 0, stream>>>(p9, wpack);
  pack64_g<<<dim3(FFNX / 64, DIMX / 64), 256, 0, stream>>>(W1, W1t, DIMX, FFNX);
  pack64_g<<<dim3(DIMX / 64, FFNX / 64), 256, 0, stream>>>(W2, W2t, FFNX, DIMX);
  pack_cvt_kernel<<<(L2X * DIMX / 4 + 255) / 256, 256, 0, stream>>>(enc, encb, L2X * DIMX / 4);
  prep_e_kernel<<<36, 256, 0, stream>>>(sst, temb, e);

  // ---- self-attention branch ----
  ln_affine_kernel<<<SEQ, 256, 0, stream>>>(hidden, e + DIMX, e, 1, normb);
  Outs qkvgo = {qb_, kb_, vb_, gb_, bq, bk, bv, bg, vbh, gbh};
  gemm2ph<6, 4, 0, 0, 0, 1><<<dim3(8, 32), 512, 0, stream>>>(normb, wpack, qkvgo, SEQ, 4 * DIMX, DIMX, DIMX);
  rms_rope2_kernel<<<dim3(SEQ, 2), 256, 0, stream>>>(qb_, kb_, qnw, knw, cosT, sinT, 1, qbh, kbh);
  block_mean3_kernel<<<dim3(NBLK, NHEAD, 3), 128, 0, stream>>>(qb_, kb_, vb_, qc, kc, vc);
  coarse_attn_kernel<<<NHEAD, 256, 0, stream>>>(qc, kc, pc, idx);
  coarse_ctx_kernel<<<dim3(NBLK, NHEAD), 128, 0, stream>>>(pc, vc, cb);
  attn_kernel<<<dim3(NBLK, NHEAD), 256, 0, stream>>>(qbh, kbh, vbh, idx, gbh, cb, mixb);
  Outs wo_o = {part4q, nullptr, nullptr, nullptr, nullptr, nullptr, nullptr, nullptr, nullptr, nullptr};
  gemm2ph<6, 1, 0, 0, 1, 1><<<dim3(8, 8, 4), 512, 0, stream>>>(mixb, Wot, wo_o, SEQ, DIMX, 384, DIMX);
  reduce_ln_kernel<<<SEQ, 256, 0, stream>>>(part4q, bo, hidden, e + 2 * DIMX,
                                            res, saw, sab, 0, normb);
  // ---- cross attention ----
  gemm2ph<6, 1, 0, 0, 1, 1><<<dim3(8, 8, 4), 512, 0, stream>>>(normb, cWqt, wo_o, SEQ, DIMX, 384, DIMX);
  reduce_rms_kernel<<<SEQ, 256, 0, stream>>>(part4q, cbq, cqnw, qbh);
  Outs ckvo = {kb_, vb_, nullptr, nullptr, cbk, cbv, nullptr, nullptr, vbh, nullptr};
  gemm_multi<2><<<dim3(24, 4), 256, 0, stream>>>(encb, cKVt, ckvo, L2X, 2 * DIMX, DIMX);
  rms_rope_kernel<<<L2X, 256, 0, stream>>>(kb_, cknw, cosT, sinT, 0, kbh);
  attn_kernel<<<dim3(NBLK, NHEAD), 256, 0, stream>>>(qbh, kbh, vbh, nullptr, nullptr, nullptr, crossb);
  gemm2ph<6, 1, 0, 0, 1, 1><<<dim3(8, 8, 4), 512, 0, stream>>>(crossb, cWot, wo_o, SEQ, DIMX, 384, DIMX);
  reduce_ln_kernel<<<SEQ, 256, 0, stream>>>(part4q, cbo, res, nullptr,
                                            outf, e + 4 * DIMX, e + 3 * DIMX, 1, normb);
  // ---- FFN ----
  gemm10<<<dim3(8, 28), 512, 0, stream>>>(normb, W1t, b1, ffh, SEQ, FFNX, DIMX);
  Outs f2o = {part4w, nullptr, nullptr, nullptr, nullptr, nullptr, nullptr, nullptr, nullptr, nullptr};
  gemm2ph<6, 1, 0, 0, 1, 1><<<dim3(8, 8, 4), 512, 0, stream>>>(ffh, W2t, f2o, SEQ, DIMX, 2240, FFNX);
  reduce_kernel<4><<<1024, 256, 0, stream>>>(part4w, b2, outf, e + 5 * DIMX, outf,
                                             SEQ * DIMX / 4, DIMX / 4);
}

// Round 15
// 489.898 us; speedup vs baseline: 1.0391x; 1.0391x over previous
//
#include <hip/hip_runtime.h>
#include <hip/hip_bf16.h>
#include <math.h>

#define DIMX 1536
#define SEQ 2048
#define L2X 512
#define NHEAD 12
#define HDIM 128
#define NBLK 32
#define FFNX 8960
#define SCALE_ATT 0.08838834764831845f

typedef __attribute__((ext_vector_type(4))) float f4;
typedef __attribute__((ext_vector_type(4))) float f32x4;
typedef __attribute__((ext_vector_type(8))) short bf16x8;
typedef __attribute__((ext_vector_type(4))) unsigned short us4;
typedef __attribute__((ext_vector_type(8))) unsigned short us8;
typedef unsigned short us;

static __device__ __forceinline__ us f2bf(float f) {
  union { float f; unsigned u; } v; v.f = f;
  unsigned r = v.u + 0x7FFFu + ((v.u >> 16) & 1u);
  return (us)(r >> 16);
}

static __device__ __forceinline__ float bf2f(us h) {
  union { unsigned u; float f; } v; v.u = ((unsigned)h) << 16;
  return v.f;
}

static __device__ __forceinline__ void gl_lds16(const us* g, us* l) {
  __builtin_amdgcn_global_load_lds(
      (const __attribute__((address_space(1))) void*)g,
      (__attribute__((address_space(3))) void*)l, 16, 0, 0);
}

#define RAW_BAR() asm volatile("s_barrier" ::: "memory")

static __device__ __forceinline__ void xcd_map2(int& bx, int& by) {
  int gx = gridDim.x, gy = gridDim.y;
  int nwg = gx * gy;
  int lin = by * gx + bx;
  int q = nwg >> 3;
  lin = (lin & 7) * q + (lin >> 3);
  bx = lin % gx;
  by = lin / gx;
}

// ---------------------------------------------------------------------------
__global__ void __launch_bounds__(256) prep_e_kernel(const float* __restrict__ sst,
                                                     const float* __restrict__ temb,
                                                     float* __restrict__ e) {
  int i = blockIdx.x * 256 + threadIdx.x;
  if (i < 6 * DIMX) e[i] = sst[i] + temb[i];
}

// ---------------------------------------------------------------------------
struct P9 { const float* s[9]; };

__global__ void __launch_bounds__(256) pack64_9(P9 ps, us* __restrict__ dst) {
  const float* __restrict__ W = ps.s[blockIdx.z];
  us* __restrict__ Wt = dst + (size_t)blockIdx.z * DIMX * DIMX;
  __shared__ float t[64][65];
  int n0 = blockIdx.x * 64, k0 = blockIdx.y * 64;
  int tid = threadIdx.x;
#pragma unroll
  for (int i = 0; i < 4; i++) {
    int c = i * 256 + tid;
    int row = c >> 4, c4 = (c & 15) * 4;
    *reinterpret_cast<f4*>(&t[row][c4]) =
        *reinterpret_cast<const f4*>(&W[(size_t)(k0 + row) * DIMX + n0 + c4]);
  }
  __syncthreads();
#pragma unroll
  for (int i = 0; i < 2; i++) {
    int c = i * 256 + tid;
    int n = c >> 3, kc = (c & 7) * 8;
    us8 h;
#pragma unroll
    for (int j = 0; j < 8; j++) h[j] = f2bf(t[kc + j][n]);
    *reinterpret_cast<us8*>(&Wt[(size_t)(n0 + n) * DIMX + k0 + kc]) = h;
  }
}

__global__ void __launch_bounds__(256) pack64_g(const float* __restrict__ W,
                                                us* __restrict__ Wt, int K, int N) {
  __shared__ float t[64][65];
  int n0 = blockIdx.x * 64, k0 = blockIdx.y * 64;
  int tid = threadIdx.x;
#pragma unroll
  for (int i = 0; i < 4; i++) {
    int c = i * 256 + tid;
    int row = c >> 4, c4 = (c & 15) * 4;
    *reinterpret_cast<f4*>(&t[row][c4]) =
        *reinterpret_cast<const f4*>(&W[(size_t)(k0 + row) * N + n0 + c4]);
  }
  __syncthreads();
#pragma unroll
  for (int i = 0; i < 2; i++) {
    int c = i * 256 + tid;
    int n = c >> 3, kc = (c & 7) * 8;
    us8 h;
#pragma unroll
    for (int j = 0; j < 8; j++) h[j] = f2bf(t[kc + j][n]);
    *reinterpret_cast<us8*>(&Wt[(size_t)(n0 + n) * K + k0 + kc]) = h;
  }
}

__global__ void __launch_bounds__(256) pack_cvt_kernel(const float* __restrict__ X,
                                                       us* __restrict__ Y, int n4) {
  int i = blockIdx.x * 256 + threadIdx.x;
  if (i < n4) {
    f4 v = *reinterpret_cast<const f4*>(&X[(size_t)i * 4]);
    us4 h; h[0] = f2bf(v[0]); h[1] = f2bf(v[1]); h[2] = f2bf(v[2]); h[3] = f2bf(v[3]);
    *reinterpret_cast<us4*>(&Y[(size_t)i * 4]) = h;
  }
}

// ---------------------------------------------------------------------------
__global__ void __launch_bounds__(256) ln_affine_kernel(
    const float* __restrict__ X, const float* __restrict__ a,
    const float* __restrict__ b, int add1, us* __restrict__ Out) {
  __shared__ float lds4[4];
  int row = blockIdx.x, t = threadIdx.x;
  const float* x = X + (size_t)row * DIMX;
  float v[6]; float s = 0.f;
#pragma unroll
  for (int i = 0; i < 6; i++) { v[i] = x[t + 256 * i]; s += v[i]; }
  for (int o = 1; o < 64; o <<= 1) s += __shfl_xor(s, o, 64);
  if ((t & 63) == 0) lds4[t >> 6] = s;
  __syncthreads();
  float mean = (lds4[0] + lds4[1] + lds4[2] + lds4[3]) * (1.f / DIMX);
  __syncthreads();
  float s2 = 0.f;
#pragma unroll
  for (int i = 0; i < 6; i++) { float c = v[i] - mean; s2 += c * c; }
  for (int o = 1; o < 64; o <<= 1) s2 += __shfl_xor(s2, o, 64);
  if ((t & 63) == 0) lds4[t >> 6] = s2;
  __syncthreads();
  float var = (lds4[0] + lds4[1] + lds4[2] + lds4[3]) * (1.f / DIMX);
  float rstd = rsqrtf(var + 1e-6f);
#pragma unroll
  for (int i = 0; i < 6; i++) {
    int c = t + 256 * i;
    float av = a[c] + (add1 ? 1.f : 0.f);
    Out[(size_t)row * DIMX + c] = f2bf((v[i] - mean) * rstd * av + b[c]);
  }
}

// ---------------------------------------------------------------------------
// fused: x = R + [g*] (sum of 4 bf16 partials + bias); Ores=x; Onorm=LN(x)
__global__ void __launch_bounds__(256) reduce_ln_kernel(
    const us* __restrict__ P, const float* __restrict__ bias,
    const float* __restrict__ R, const float* __restrict__ g,
    float* __restrict__ Ores, const float* __restrict__ a,
    const float* __restrict__ b, int add1, us* __restrict__ Onorm) {
  __shared__ float lds4[4];
  int row = blockIdx.x, t = threadIdx.x;
  const size_t RN = (size_t)SEQ * DIMX;
  float v[6]; float s = 0.f;
#pragma unroll
  for (int i = 0; i < 6; i++) {
    int c = t + 256 * i;
    size_t ix = (size_t)row * DIMX + c;
    float x = bf2f(P[ix]);
    x += bf2f(P[RN + ix]); x += bf2f(P[2 * RN + ix]); x += bf2f(P[3 * RN + ix]);
    x += bias[c];
    x = g ? (R[ix] + g[c] * x) : (R[ix] + x);
    Ores[ix] = x;
    v[i] = x; s += x;
  }
  for (int o = 1; o < 64; o <<= 1) s += __shfl_xor(s, o, 64);
  if ((t & 63) == 0) lds4[t >> 6] = s;
  __syncthreads();
  float mean = (lds4[0] + lds4[1] + lds4[2] + lds4[3]) * (1.f / DIMX);
  __syncthreads();
  float s2 = 0.f;
#pragma unroll
  for (int i = 0; i < 6; i++) { float c = v[i] - mean; s2 += c * c; }
  for (int o = 1; o < 64; o <<= 1) s2 += __shfl_xor(s2, o, 64);
  if ((t & 63) == 0) lds4[t >> 6] = s2;
  __syncthreads();
  float var = (lds4[0] + lds4[1] + lds4[2] + lds4[3]) * (1.f / DIMX);
  float rstd = rsqrtf(var + 1e-6f);
#pragma unroll
  for (int i = 0; i < 6; i++) {
    int c = t + 256 * i;
    float av = a[c] + (add1 ? 1.f : 0.f);
    Onorm[(size_t)row * DIMX + c] = f2bf((v[i] - mean) * rstd * av + b[c]);
  }
}

// ---------------------------------------------------------------------------
// fused cross-Q: x = sum of 4 bf16 partials + bias; Ob = bf16(RMS(x)*w)
__global__ void __launch_bounds__(256) reduce_rms_kernel(
    const us* __restrict__ P, const float* __restrict__ bias,
    const float* __restrict__ w, us* __restrict__ Ob) {
  __shared__ float lds4[4];
  int row = blockIdx.x, t = threadIdx.x;
  const size_t RN = (size_t)SEQ * DIMX;
  float v[6]; float s2 = 0.f;
#pragma unroll
  for (int i = 0; i < 6; i++) {
    int c = t + 256 * i;
    size_t ix = (size_t)row * DIMX + c;
    float x = bf2f(P[ix]);
    x += bf2f(P[RN + ix]); x += bf2f(P[2 * RN + ix]); x += bf2f(P[3 * RN + ix]);
    x += bias[c];
    v[i] = x; s2 += x * x;
  }
  for (int o = 1; o < 64; o <<= 1) s2 += __shfl_xor(s2, o, 64);
  if ((t & 63) == 0) lds4[t >> 6] = s2;
  __syncthreads();
  float ms = (lds4[0] + lds4[1] + lds4[2] + lds4[3]) * (1.f / DIMX);
  float rstd = rsqrtf(ms + 1e-6f);
#pragma unroll
  for (int i = 0; i < 6; i++) {
    int c = t + 256 * i;
    float y = v[i] * (rstd * w[c]);
    Ob[(size_t)row * DIMX + c] = f2bf(y);
  }
}

// ---------------------------------------------------------------------------
// fused q+k RMS(+RoPE): z=blockIdx.y selects stream; in-place f32 + bf16 mirror
__global__ void __launch_bounds__(256) rms_rope2_kernel(
    float* __restrict__ X0, float* __restrict__ X1,
    const float* __restrict__ w0, const float* __restrict__ w1,
    const float* __restrict__ cosT, const float* __restrict__ sinT, int do_rope,
    us* __restrict__ O0, us* __restrict__ O1) {
  __shared__ float lds4[4];
  int row = blockIdx.x, t = threadIdx.x;
  float* x = (blockIdx.y ? X1 : X0) + (size_t)row * DIMX;
  const float* wgt = blockIdx.y ? w1 : w0;
  us* Ob = blockIdx.y ? O1 : O0;
  int base = t * 6;
  float v[6]; float s2 = 0.f;
#pragma unroll
  for (int i = 0; i < 6; i++) { v[i] = x[base + i]; s2 += v[i] * v[i]; }
  for (int o = 1; o < 64; o <<= 1) s2 += __shfl_xor(s2, o, 64);
  if ((t & 63) == 0) lds4[t >> 6] = s2;
  __syncthreads();
  float ms = (lds4[0] + lds4[1] + lds4[2] + lds4[3]) * (1.f / DIMX);
  float rstd = rsqrtf(ms + 1e-6f);
#pragma unroll
  for (int i = 0; i < 6; i++) v[i] *= rstd * wgt[base + i];
  if (do_rope) {
#pragma unroll
    for (int j = 0; j < 3; j++) {
      int c = base + 2 * j;
      int pi = (c & (HDIM - 1)) >> 1;
      float cs = cosT[row * (HDIM / 2) + pi], sn = sinT[row * (HDIM / 2) + pi];
      float ev = v[2 * j], ov = v[2 * j + 1];
      v[2 * j] = ev * cs - ov * sn;
      v[2 * j + 1] = ov * cs + ev * sn;
    }
  }
#pragma unroll
  for (int i = 0; i < 6; i++) {
    x[base + i] = v[i];
    Ob[(size_t)row * DIMX + base + i] = f2bf(v[i]);
  }
}

// single-stream variant (cross-attn k)
__global__ void __launch_bounds__(256) rms_rope_kernel(
    float* __restrict__ X, const float* __restrict__ wgt,
    const float* __restrict__ cosT, const float* __restrict__ sinT, int do_rope,
    us* __restrict__ Ob) {
  __shared__ float lds4[4];
  int row = blockIdx.x, t = threadIdx.x;
  float* x = X + (size_t)row * DIMX;
  int base = t * 6;
  float v[6]; float s2 = 0.f;
#pragma unroll
  for (int i = 0; i < 6; i++) { v[i] = x[base + i]; s2 += v[i] * v[i]; }
  for (int o = 1; o < 64; o <<= 1) s2 += __shfl_xor(s2, o, 64);
  if ((t & 63) == 0) lds4[t >> 6] = s2;
  __syncthreads();
  float ms = (lds4[0] + lds4[1] + lds4[2] + lds4[3]) * (1.f / DIMX);
  float rstd = rsqrtf(ms + 1e-6f);
#pragma unroll
  for (int i = 0; i < 6; i++) v[i] *= rstd * wgt[base + i];
  if (do_rope) {
#pragma unroll
    for (int j = 0; j < 3; j++) {
      int c = base + 2 * j;
      int pi = (c & (HDIM - 1)) >> 1;
      float cs = cosT[row * (HDIM / 2) + pi], sn = sinT[row * (HDIM / 2) + pi];
      float ev = v[2 * j], ov = v[2 * j + 1];
      v[2 * j] = ev * cs - ov * sn;
      v[2 * j + 1] = ov * cs + ev * sn;
    }
  }
#pragma unroll
  for (int i = 0; i < 6; i++) {
    x[base + i] = v[i];
    Ob[(size_t)row * DIMX + base + i] = f2bf(v[i]);
  }
}

// ---------------------------------------------------------------------------
struct Outs {
  float *o0, *o1, *o2, *o3;
  const float *b0, *b1, *b2, *b3;
  us* ob;   // bf16 mirror (V) / bf16 split-K partial base
  us* ob2;  // bf16-only output for chunk 3 (G)
};

// ===========================================================================
// gemm2ph: 8-wave (4M x 2N) 256 x (NP*32) tile, BK=64, 2 phases/K-tile,
// counted vmcnt tail-pinning. SPLITK=1: bf16 partials to outs.ob.
// ===========================================================================
template<int NP, int NCHUNK, int OUT_BF16, int DO_GELU, int SPLITK, int DIRECT>
__global__ void __launch_bounds__(512, 2) gemm2ph(
    const us* __restrict__ A, const us* __restrict__ Bt,
    Outs outs, int M, int N, int K, int Kfull) {
  constexpr int NT = NP * 32;
  constexpr int TOT = 16384 + NT * 64;
  constexpr int BI = (NT * 8 + 511) / 512;
  constexpr int NH0 = NP / 2;
  constexpr int NH1 = NP - NH0;
  __shared__ __align__(16) us S[2 * TOT];
  const int tid = threadIdx.x;
  const int lane = tid & 63;
  const int wid = tid >> 6;
  const int wr = wid >> 1, wc = wid & 1;
  const int fr = lane & 15, xo = lane >> 4;
  const int r7 = fr & 7, q4 = xo * 4;
  int tm, tn;
  if (DIRECT) {
    tm = blockIdx.x * 256; tn = blockIdx.y * NT;
  } else {
    int bx = blockIdx.x, by = blockIdx.y;
    xcd_map2(bx, by);
    tm = by * 256; tn = bx * NT;
  }
  const size_t kb = SPLITK ? (size_t)blockIdx.z * K : 0;

  auto stA = [&](int buf, int k0) {
#pragma unroll
    for (int i = 0; i < 4; i++) {
      int c = i * 512 + tid;
      gl_lds16(A + (size_t)(tm + (c >> 3)) * Kfull + kb + k0 + (((c & 7) ^ ((c >> 3) & 7)) * 8),
               S + buf * TOT + (i * 512 + wid * 64) * 8);
    }
  };
  auto stB = [&](int buf, int k0) {
#pragma unroll
    for (int i = 0; i < BI; i++) {
      int c = i * 512 + tid;
      if (c < NT * 8)
        gl_lds16(Bt + (size_t)(tn + (c >> 3)) * Kfull + kb + k0 + (((c & 7) ^ ((c >> 3) & 7)) * 8),
                 S + buf * TOT + 16384 + (i * 512 + wid * 64) * 8);
    }
  };
  auto rdA = [&](int buf, int mp, int ks) -> bf16x8 {
    int r = wr * 64 + mp * 16 + fr;
    int ko = ((ks * 4 + xo) ^ r7) * 8;
    return *reinterpret_cast<const bf16x8*>(&S[buf * TOT + r * 64 + ko]);
  };
  auto rdB = [&](int buf, int np, int ks) -> bf16x8 {
    int r = wc * (NP * 16) + np * 16 + fr;
    int ko = ((ks * 4 + xo) ^ r7) * 8;
    return *reinterpret_cast<const bf16x8*>(&S[buf * TOT + 16384 + r * 64 + ko]);
  };

  f32x4 acc[4][NP];
#pragma unroll
  for (int m = 0; m < 4; m++)
#pragma unroll
    for (int n = 0; n < NP; n++) acc[m][n] = (f32x4)(0.f);
  bf16x8 aF[2][4], bFr[2][NH1 > NH0 ? NH1 : NH0];

  const int nt = K >> 6;
  stA(0, 0); stB(0, 0); stA(1, 64);
  asm volatile("s_waitcnt vmcnt(4)" ::: "memory");
  RAW_BAR();

  for (int t = 0; t < nt; t++) {
    const int buf = t & 1;
    const int k1 = (t + 1) << 6, k2 = (t + 2) << 6;
#pragma unroll
    for (int ks = 0; ks < 2; ks++)
#pragma unroll
      for (int m = 0; m < 4; m++) aF[ks][m] = rdA(buf, m, ks);
#pragma unroll
    for (int ks = 0; ks < 2; ks++)
#pragma unroll
      for (int n = 0; n < NH0; n++) bFr[ks][n] = rdB(buf, n, ks);
    if (t + 1 < nt) stB(buf ^ 1, k1);
    RAW_BAR();
    __builtin_amdgcn_s_setprio(1);
#pragma unroll
    for (int ks = 0; ks < 2; ks++)
#pragma unroll
      for (int m = 0; m < 4; m++)
#pragma unroll
        for (int n = 0; n < NH0; n++)
          acc[m][n] = __builtin_amdgcn_mfma_f32_16x16x32_bf16(aF[ks][m], bFr[ks][n], acc[m][n], 0, 0, 0);
    __builtin_amdgcn_s_setprio(0);
    RAW_BAR();
#pragma unroll
    for (int ks = 0; ks < 2; ks++)
#pragma unroll
      for (int n = 0; n < NH1; n++) bFr[ks][n] = rdB(buf, NH0 + n, ks);
    if (t + 2 < nt) stA(buf, k2);
    RAW_BAR();
    __builtin_amdgcn_s_setprio(1);
#pragma unroll
    for (int ks = 0; ks < 2; ks++)
#pragma unroll
      for (int m = 0; m < 4; m++)
#pragma unroll
        for (int n = 0; n < NH1; n++)
          acc[m][NH0 + n] = __builtin_amdgcn_mfma_f32_16x16x32_bf16(aF[ks][m], bFr[ks][n], acc[m][NH0 + n], 0, 0, 0);
    __builtin_amdgcn_s_setprio(0);
    if (t + 2 < nt) asm volatile("s_waitcnt vmcnt(4)" ::: "memory");
    else            asm volatile("s_waitcnt vmcnt(0)" ::: "memory");
    RAW_BAR();
  }

#pragma unroll
  for (int m = 0; m < 4; m++)
#pragma unroll
    for (int n = 0; n < NP; n++) {
      int col = tn + wc * (NP * 16) + n * 16 + fr;
      int rowb = tm + wr * 64 + m * 16 + q4;
      if (SPLITK) {
        us* Pb = outs.ob + (size_t)blockIdx.z * M * N;
#pragma unroll
        for (int r = 0; r < 4; r++)
          Pb[(size_t)(rowb + r) * N + col] = f2bf(acc[m][n][r]);
      } else {
        int c2; float* op; const float* bp; int sel = 0;
        if constexpr (NCHUNK == 1) {
          c2 = col; op = outs.o0; bp = outs.b0;
        } else {
          sel = col >= 3 * DIMX ? 3 : (col >= 2 * DIMX ? 2 : (col >= DIMX ? 1 : 0));
          c2 = col - sel * DIMX;
          op = sel == 0 ? outs.o0 : (sel == 1 ? outs.o1 : (sel == 2 ? outs.o2 : outs.o3));
          bp = sel == 0 ? outs.b0 : (sel == 1 ? outs.b1 : (sel == 2 ? outs.b2 : outs.b3));
        }
        float bv = bp[c2];
#pragma unroll
        for (int r = 0; r < 4; r++) {
          float v = acc[m][n][r] + bv;
          if (DO_GELU) {
            float u = 1.5957691216057308f * (v + 0.044715f * v * v * v);
            v = v / (1.f + __expf(-u));
          }
          if (OUT_BF16)
            outs.ob[(size_t)(rowb + r) * N + col] = f2bf(v);
          else if (NCHUNK == 4 && outs.ob2 != nullptr && sel == 3) {
            outs.ob2[(size_t)(rowb + r) * DIMX + c2] = f2bf(v);  // G: bf16 only
          } else {
            op[(size_t)(rowb + r) * DIMX + c2] = v;
            if (NCHUNK == 4 && outs.ob != nullptr && sel == 2)
              outs.ob[(size_t)(rowb + r) * DIMX + c2] = f2bf(v);
          }
        }
      }
    }
}

// ===========================================================================
// gemm10: FFN1 — 256x320 tile, 2M x 4N waves, sequential-ks 2-phase.
// ===========================================================================
__global__ void __launch_bounds__(512, 2) gemm10(
    const us* __restrict__ A, const us* __restrict__ Bt,
    const float* __restrict__ bias, us* __restrict__ Cb,
    int M, int N, int K) {
  constexpr int NT = 320;
  constexpr int TOT = 16384 + NT * 64;
  __shared__ __align__(16) us S[2 * TOT];
  const int tid = threadIdx.x;
  const int lane = tid & 63;
  const int wid = tid >> 6;
  const int wr = wid >> 2, wc = wid & 3;
  const int fr = lane & 15, xo = lane >> 4;
  const int r7 = fr & 7, q4 = xo * 4;
  const int tm = blockIdx.x * 256, tn = blockIdx.y * NT;

  auto stA = [&](int buf, int k0) {
#pragma unroll
    for (int i = 0; i < 4; i++) {
      int c = i * 512 + tid;
      gl_lds16(A + (size_t)(tm + (c >> 3)) * K + k0 + (((c & 7) ^ ((c >> 3) & 7)) * 8),
               S + buf * TOT + (i * 512 + wid * 64) * 8);
    }
  };
  auto stB = [&](int buf, int k0) {
#pragma unroll
    for (int i = 0; i < 5; i++) {
      int c = i * 512 + tid;
      gl_lds16(Bt + (size_t)(tn + (c >> 3)) * K + k0 + (((c & 7) ^ ((c >> 3) & 7)) * 8),
               S + buf * TOT + 16384 + (i * 512 + wid * 64) * 8);
    }
  };
  auto rdA = [&](int buf, int mp, int ks) -> bf16x8 {
    int r = wr * 128 + mp * 16 + fr;
    int ko = ((ks * 4 + xo) ^ r7) * 8;
    return *reinterpret_cast<const bf16x8*>(&S[buf * TOT + r * 64 + ko]);
  };
  auto rdB = [&](int buf, int np, int ks) -> bf16x8 {
    int r = wc * 80 + np * 16 + fr;
    int ko = ((ks * 4 + xo) ^ r7) * 8;
    return *reinterpret_cast<const bf16x8*>(&S[buf * TOT + 16384 + r * 64 + ko]);
  };

  f32x4 acc[8][5];
#pragma unroll
  for (int m = 0; m < 8; m++)
#pragma unroll
    for (int n = 0; n < 5; n++) acc[m][n] = (f32x4)(0.f);
  bf16x8 aF[8], bF[5];

  const int nt = K >> 6;
  stA(0, 0); stB(0, 0); stA(1, 64);
  asm volatile("s_waitcnt vmcnt(4)" ::: "memory");
  RAW_BAR();

  for (int t = 0; t < nt; t++) {
    const int buf = t & 1;
    const int k1 = (t + 1) << 6, k2 = (t + 2) << 6;
#pragma unroll
    for (int m = 0; m < 8; m++) aF[m] = rdA(buf, m, 0);
#pragma unroll
    for (int n = 0; n < 5; n++) bF[n] = rdB(buf, n, 0);
    if (t + 1 < nt) stB(buf ^ 1, k1);
    RAW_BAR();
    __builtin_amdgcn_s_setprio(1);
#pragma unroll
    for (int m = 0; m < 8; m++)
#pragma unroll
      for (int n = 0; n < 5; n++)
        acc[m][n] = __builtin_amdgcn_mfma_f32_16x16x32_bf16(aF[m], bF[n], acc[m][n], 0, 0, 0);
    __builtin_amdgcn_s_setprio(0);
    RAW_BAR();
#pragma unroll
    for (int m = 0; m < 8; m++) aF[m] = rdA(buf, m, 1);
#pragma unroll
    for (int n = 0; n < 5; n++) bF[n] = rdB(buf, n, 1);
    if (t + 2 < nt) stA(buf, k2);
    RAW_BAR();
    __builtin_amdgcn_s_setprio(1);
#pragma unroll
    for (int m = 0; m < 8; m++)
#pragma unroll
      for (int n = 0; n < 5; n++)
        acc[m][n] = __builtin_amdgcn_mfma_f32_16x16x32_bf16(aF[m], bF[n], acc[m][n], 0, 0, 0);
    __builtin_amdgcn_s_setprio(0);
    if (t + 2 < nt) asm volatile("s_waitcnt vmcnt(4)" ::: "memory");
    else            asm volatile("s_waitcnt vmcnt(0)" ::: "memory");
    RAW_BAR();
  }

#pragma unroll
  for (int m = 0; m < 8; m++)
#pragma unroll
    for (int n = 0; n < 5; n++) {
      int col = tn + wc * 80 + n * 16 + fr;
      int rowb = tm + wr * 128 + m * 16 + q4;
      float bv = bias[col];
#pragma unroll
      for (int r = 0; r < 4; r++) {
        float v = acc[m][n][r] + bv;
        float u = 1.5957691216057308f * (v + 0.044715f * v * v * v);
        v = v / (1.f + __expf(-u));
        Cb[(size_t)(rowb + r) * N + col] = f2bf(v);
      }
    }
}

// ---------------------------------------------------------------------------
// 128x128 kernel for the small cross-KV GEMM; chunk 1 (V) writes bf16 to ob.
template<int NCHUNK>
__global__ void __launch_bounds__(256) gemm_multi(
    const us* __restrict__ A, const us* __restrict__ Bt,
    Outs outs, int M, int N, int K) {
  __shared__ __align__(16) us As[128 * 64];
  __shared__ __align__(16) us Bs[128 * 64];
  const int tid = threadIdx.x;
  const int lane = tid & 63;
  const int w = tid >> 6;
  const int wr = w >> 1, wc = w & 1;
  const int fr = lane & 15;
  const int xo = lane >> 4;
  const int r7 = fr & 7;
  const int q4 = xo * 4;
  int bx = blockIdx.x, by = blockIdx.y;
  xcd_map2(bx, by);
  const int tm = by * 128, tn = bx * 128;

  f32x4 acc[4][4];
#pragma unroll
  for (int m = 0; m < 4; m++)
#pragma unroll
    for (int n = 0; n < 4; n++) acc[m][n] = (f32x4)(0.f);

  int srow[4], skc[4];
#pragma unroll
  for (int j = 0; j < 4; j++) {
    int c = j * 256 + tid;
    srow[j] = c >> 3;
    skc[j] = ((c & 7) ^ ((c >> 3) & 7)) * 8;
  }

  for (int k0 = 0; k0 < K; k0 += 64) {
#pragma unroll
    for (int j = 0; j < 4; j++) {
      gl_lds16(A + (size_t)(tm + srow[j]) * K + k0 + skc[j], As + (j * 256 + w * 64) * 8);
      gl_lds16(Bt + (size_t)(tn + srow[j]) * K + k0 + skc[j], Bs + (j * 256 + w * 64) * 8);
    }
    __syncthreads();
    bf16x8 af[2][4], bfv[2][4];
#pragma unroll
    for (int ks = 0; ks < 2; ks++) {
      const int koff = (((ks * 4 + xo) ^ r7) << 3);
#pragma unroll
      for (int m = 0; m < 4; m++)
        af[ks][m] = *reinterpret_cast<const bf16x8*>(&As[(wr * 64 + m * 16 + fr) * 64 + koff]);
#pragma unroll
      for (int n = 0; n < 4; n++)
        bfv[ks][n] = *reinterpret_cast<const bf16x8*>(&Bs[(wc * 64 + n * 16 + fr) * 64 + koff]);
    }
#pragma unroll
    for (int ks = 0; ks < 2; ks++)
#pragma unroll
      for (int m = 0; m < 4; m++)
#pragma unroll
        for (int n = 0; n < 4; n++)
          acc[m][n] = __builtin_amdgcn_mfma_f32_16x16x32_bf16(af[ks][m], bfv[ks][n], acc[m][n], 0, 0, 0);
    __syncthreads();
  }
#pragma unroll
  for (int m = 0; m < 4; m++) {
#pragma unroll
    for (int n = 0; n < 4; n++) {
      int col = tn + wc * 64 + n * 16 + fr;
      int c2; float* op; const float* bp; int sel = 0;
      if constexpr (NCHUNK == 2) {
        sel = col >= DIMX;
        c2 = col - sel * DIMX;
        op = sel ? outs.o1 : outs.o0;
        bp = sel ? outs.b1 : outs.b0;
      } else {
        c2 = col; op = outs.o0; bp = outs.b0;
      }
      float bv = bp[c2];
#pragma unroll
      for (int r = 0; r < 4; r++) {
        int row = tm + wr * 64 + m * 16 + q4 + r;
        float v = acc[m][n][r] + bv;
        if (NCHUNK == 2 && outs.ob != nullptr && sel == 1)
          outs.ob[(size_t)row * DIMX + c2] = f2bf(v);
        else
          op[(size_t)row * DIMX + c2] = v;
      }
    }
  }
}

// reduce for FFN2: bf16 partials, f32 out with residual+gate
__global__ void __launch_bounds__(256) reduce4h_kernel(
    const us* __restrict__ P, const float* __restrict__ bias,
    const float* __restrict__ R, const float* __restrict__ g,
    float* __restrict__ O, int total4, int ncol4) {
  const size_t RN = (size_t)total4 * 4;
  for (int i = blockIdx.x * 256 + threadIdx.x; i < total4; i += gridDim.x * 256) {
    size_t base = (size_t)i * 4;
    us4 p0 = *reinterpret_cast<const us4*>(&P[base]);
    us4 p1 = *reinterpret_cast<const us4*>(&P[RN + base]);
    us4 p2 = *reinterpret_cast<const us4*>(&P[2 * RN + base]);
    us4 p3 = *reinterpret_cast<const us4*>(&P[3 * RN + base]);
    int c4 = (i % ncol4) * 4;
    f4 bvec = *reinterpret_cast<const f4*>(&bias[c4]);
    f4 gv = *reinterpret_cast<const f4*>(&g[c4]);
    const f4 rv = *reinterpret_cast<const f4*>(&R[base]);
    f4 s;
#pragma unroll
    for (int j = 0; j < 4; j++) {
      float x = bf2f(p0[j]) + bf2f(p1[j]) + bf2f(p2[j]) + bf2f(p3[j]) + bvec[j];
      s[j] = rv[j] + gv[j] * x;
    }
    *reinterpret_cast<f4*>(&O[base]) = s;
  }
}

// ---------------------------------------------------------------------------
// block-sparse flash attention, wave-owns-rows + T14 async reg-staging +
// T13 defer-max. G gate is bf16.
__global__ void __launch_bounds__(256) attn_kernel(
    const us* __restrict__ Q, const us* __restrict__ Kx,
    const us* __restrict__ V, const int* __restrict__ idx,
    const us* __restrict__ G, const float* __restrict__ CB,
    us* __restrict__ Out) {
  __shared__ us k_s[64 * 136];
  __shared__ us vT_s[128 * 72];
  __shared__ us p_s[4][16 * 72];

  const int qb = blockIdx.x;
  const int h = blockIdx.y;
  const int tid = threadIdx.x;
  const int lane = tid & 63;
  const int w = tid >> 6;
  const int fr = lane & 15;
  const int xo = lane >> 4;
  const int k8 = xo * 8;
  const int q4 = xo * 4;
  const int vd = tid & 127, vth = (tid >> 7) * 32;

  bf16x8 qF[4];
#pragma unroll
  for (int kk = 0; kk < 4; kk++)
    qF[kk] = *reinterpret_cast<const bf16x8*>(
        &Q[(size_t)(qb * 64 + w * 16 + fr) * DIMX + h * HDIM + kk * 32 + k8]);

  us8 kR[4], vR[4];
  auto loadTile = [&](int blk) {
#pragma unroll
    for (int i = 0; i < 4; i++) {
      int c = i * 256 + tid;
      int row = c >> 4, d8 = (c & 15) * 8;
      kR[i] = *reinterpret_cast<const us8*>(&Kx[(size_t)(blk * 64 + row) * DIMX + h * HDIM + d8]);
    }
#pragma unroll
    for (int j = 0; j < 4; j++) {
      us8 hv;
#pragma unroll
      for (int qq = 0; qq < 8; qq++)
        hv[qq] = V[(size_t)(blk * 64 + vth + j * 8 + qq) * DIMX + h * HDIM + vd];
      vR[j] = hv;
    }
  };

  float m_[4], l_[4];
#pragma unroll
  for (int r = 0; r < 4; r++) { m_[r] = -1e30f; l_[r] = 0.f; }
  f32x4 acc[8];
#pragma unroll
  for (int n = 0; n < 8; n++) acc[n] = (f32x4)(0.f);

  {
    int blk0 = idx ? idx[(h * NBLK + qb) * 8 + 0] : 0;
    loadTile(blk0);
  }

  for (int ib = 0; ib < 8; ib++) {
    __syncthreads();
#pragma unroll
    for (int i = 0; i < 4; i++) {
      int c = i * 256 + tid;
      int row = c >> 4, d8 = (c & 15) * 8;
      *reinterpret_cast<us8*>(&k_s[row * 136 + d8]) = kR[i];
    }
#pragma unroll
    for (int j = 0; j < 4; j++)
      *reinterpret_cast<us8*>(&vT_s[vd * 72 + vth + j * 8]) = vR[j];
    __syncthreads();
    if (ib + 1 < 8) {
      int blkn = idx ? idx[(h * NBLK + qb) * 8 + ib + 1] : ib + 1;
      loadTile(blkn);
    }
    f32x4 accs[4];
#pragma unroll
    for (int n = 0; n < 4; n++) accs[n] = (f32x4)(0.f);
#pragma unroll
    for (int kk = 0; kk < 4; kk++)
#pragma unroll
      for (int n = 0; n < 4; n++) {
        bf16x8 kb = *reinterpret_cast<const bf16x8*>(&k_s[(n * 16 + fr) * 136 + kk * 32 + k8]);
        accs[n] = __builtin_amdgcn_mfma_f32_16x16x32_bf16(qF[kk], kb, accs[n], 0, 0, 0);
      }
#pragma unroll
    for (int n = 0; n < 4; n++)
#pragma unroll
      for (int r = 0; r < 4; r++) accs[n][r] *= SCALE_ATT;
    float vmax[4];
#pragma unroll
    for (int r = 0; r < 4; r++) {
      float v = fmaxf(fmaxf(accs[0][r], accs[1][r]), fmaxf(accs[2][r], accs[3][r]));
      for (int o = 1; o < 16; o <<= 1) v = fmaxf(v, __shfl_xor(v, o, 64));
      vmax[r] = v;
    }
    int need = 0;
#pragma unroll
    for (int r = 0; r < 4; r++) need |= (vmax[r] - m_[r] > 8.f) ? 1 : 0;
    if (__any(need)) {
      float al[4];
#pragma unroll
      for (int r = 0; r < 4; r++) {
        float mn = fmaxf(m_[r], vmax[r]);
        al[r] = __expf(m_[r] - mn);
        m_[r] = mn;
        l_[r] *= al[r];
      }
#pragma unroll
      for (int n = 0; n < 8; n++) {
        acc[n][0] *= al[0]; acc[n][1] *= al[1];
        acc[n][2] *= al[2]; acc[n][3] *= al[3];
      }
    }
    float ps[4] = {0.f, 0.f, 0.f, 0.f};
#pragma unroll
    for (int n = 0; n < 4; n++)
#pragma unroll
      for (int r = 0; r < 4; r++) {
        float p = __expf(accs[n][r] - m_[r]);
        p_s[w][(q4 + r) * 72 + n * 16 + fr] = f2bf(p);
        ps[r] += p;
      }
#pragma unroll
    for (int r = 0; r < 4; r++) {
      float sv = ps[r];
      for (int o = 1; o < 16; o <<= 1) sv += __shfl_xor(sv, o, 64);
      l_[r] += sv;
    }
    bf16x8 pa[2];
#pragma unroll
    for (int ks = 0; ks < 2; ks++)
      pa[ks] = *reinterpret_cast<const bf16x8*>(&p_s[w][fr * 72 + ks * 32 + k8]);
#pragma unroll
    for (int ks = 0; ks < 2; ks++)
#pragma unroll
      for (int n = 0; n < 8; n++) {
        bf16x8 vb = *reinterpret_cast<const bf16x8*>(&vT_s[(n * 16 + fr) * 72 + ks * 32 + k8]);
        acc[n] = __builtin_amdgcn_mfma_f32_16x16x32_bf16(pa[ks], vb, acc[n], 0, 0, 0);
      }
  }
#pragma unroll
  for (int n = 0; n < 8; n++)
#pragma unroll
    for (int r = 0; r < 4; r++) {
      int srow = qb * 64 + w * 16 + q4 + r;
      int d = n * 16 + fr;
      float o = acc[n][r] / l_[r];
      size_t oi = (size_t)srow * DIMX + h * HDIM + d;
      if (G) o += bf2f(G[oi]) * CB[(size_t)qb * DIMX + h * HDIM + d];
      Out[oi] = f2bf(o);
    }
}

// ---------------------------------------------------------------------------
__global__ void __launch_bounds__(128) block_mean3_kernel(const float* __restrict__ q,
                                                          const float* __restrict__ k,
                                                          const float* __restrict__ v,
                                                          float* __restrict__ qc,
                                                          float* __restrict__ kc,
                                                          float* __restrict__ vc) {
  int n = blockIdx.x, h = blockIdx.y, z = blockIdx.z, d = threadIdx.x;
  const float* X = z == 0 ? q : (z == 1 ? k : v);
  float* O = z == 0 ? qc : (z == 1 ? kc : vc);
  float s = 0.f;
  for (int t = 0; t < 64; t++) s += X[(size_t)(n * 64 + t) * DIMX + h * HDIM + d];
  O[(n * NHEAD + h) * HDIM + d] = s * (1.f / 64.f);
}

__global__ void __launch_bounds__(256) coarse_attn_kernel(const float* __restrict__ qc,
                                                          const float* __restrict__ kc,
                                                          float* __restrict__ pc,
                                                          int* __restrict__ idxout) {
  int h = blockIdx.x, t = threadIdx.x;
  __shared__ float sm[32][32];
  for (int p = t; p < 1024; p += 256) {
    int n = p >> 5, m = p & 31;
    float dot = 0.f;
    for (int d = 0; d < HDIM; d++)
      dot += qc[n * DIMX + h * HDIM + d] * kc[m * DIMX + h * HDIM + d];
    sm[n][m] = dot * SCALE_ATT;
  }
  __syncthreads();
  if (t < 32) {
    int n = t;
    float mx = -1e30f;
#pragma unroll
    for (int m = 0; m < 32; m++) mx = fmaxf(mx, sm[n][m]);
    float pv[32]; float ssum = 0.f;
#pragma unroll
    for (int m = 0; m < 32; m++) { pv[m] = __expf(sm[n][m] - mx); ssum += pv[m]; }
    float inv = 1.f / ssum;
#pragma unroll
    for (int m = 0; m < 32; m++) { pv[m] *= inv; pc[(h * 32 + n) * 32 + m] = pv[m]; }
    unsigned chosen = 0;
    for (int i = 0; i < 8; i++) {
      float best = -1.f; int bi = 0;
#pragma unroll
      for (int m = 0; m < 32; m++)
        if (!((chosen >> m) & 1u) && pv[m] > best) { best = pv[m]; bi = m; }
      chosen |= 1u << bi;
      idxout[(h * 32 + n) * 8 + i] = bi;
    }
  }
}

__global__ void __launch_bounds__(128) coarse_ctx_kernel(const float* __restrict__ pc,
                                                         const float* __restrict__ vc,
                                                         float* __restrict__ cb) {
  int n = blockIdx.x, h = blockIdx.y, d = threadIdx.x;
  float s = 0.f;
  for (int m = 0; m < 32; m++)
    s += pc[(h * 32 + n) * 32 + m] * vc[(m * NHEAD + h) * HDIM + d];
  cb[(n * NHEAD + h) * HDIM + d] = s;
}

// ---------------------------------------------------------------------------
extern "C" void kernel_launch(void* const* d_in, const int* in_sizes, int n_in,
                              void* d_out, int out_size, void* d_ws, size_t ws_size,
                              hipStream_t stream) {
  (void)in_sizes; (void)n_in; (void)out_size; (void)ws_size;
  const float* hidden = (const float*)d_in[0];
  const float* enc    = (const float*)d_in[1];
  const float* temb   = (const float*)d_in[2];
  const float* cosT   = (const float*)d_in[3];
  const float* sinT   = (const float*)d_in[4];
  const float* sst    = (const float*)d_in[5];
  const float* Wq = (const float*)d_in[6];   const float* bq = (const float*)d_in[7];
  const float* Wk = (const float*)d_in[8];   const float* bk = (const float*)d_in[9];
  const float* Wv = (const float*)d_in[10];  const float* bv = (const float*)d_in[11];
  const float* Wg = (const float*)d_in[12];  const float* bg = (const float*)d_in[13];
  const float* Wo = (const float*)d_in[14];  const float* bo = (const float*)d_in[15];
  const float* qnw = (const float*)d_in[16]; const float* knw = (const float*)d_in[17];
  const float* saw = (const float*)d_in[18]; const float* sab = (const float*)d_in[19];
  const float* cWq = (const float*)d_in[20]; const float* cbq = (const float*)d_in[21];
  const float* cWk = (const float*)d_in[22]; const float* cbk = (const float*)d_in[23];
  const float* cWv = (const float*)d_in[24]; const float* cbv = (const float*)d_in[25];
  const float* cWo = (const float*)d_in[26]; const float* cbo = (const float*)d_in[27];
  const float* cqnw = (const float*)d_in[28]; const float* cknw = (const float*)d_in[29];
  const float* W1 = (const float*)d_in[30];  const float* b1 = (const float*)d_in[31];
  const float* W2 = (const float*)d_in[32];  const float* b2 = (const float*)d_in[33];

  char* ws = (char*)d_ws;
  size_t off = 0;
  auto alloc = [&](size_t bytes) -> void* {
    void* p = ws + off;
    off += (bytes + 255) & ~(size_t)255;
    return p;
  };
  const size_t SD = (size_t)SEQ * DIMX * 4;
  const size_t SDh = (size_t)SEQ * DIMX * 2;
  const size_t WSQ = (size_t)DIMX * DIMX * 2;
  float* e     = (float*)alloc(6 * DIMX * 4);
  us* normb    = (us*)alloc(SDh);
  float* qb_   = (float*)alloc(SD);   // qb_..gb_ contiguous
  float* kb_   = (float*)alloc(SD);
  float* vb_   = (float*)alloc(SD);
  float* gb_   = (float*)alloc(SD);
  us* qbh      = (us*)alloc(SDh);
  us* kbh      = (us*)alloc(SDh);
  us* vbh      = (us*)alloc(SDh);
  us* gbh      = (us*)alloc(SDh);
  float* qc    = (float*)alloc((size_t)NBLK * DIMX * 4);
  float* kc    = (float*)alloc((size_t)NBLK * DIMX * 4);
  float* vc    = (float*)alloc((size_t)NBLK * DIMX * 4);
  float* pc    = (float*)alloc(NHEAD * 32 * 32 * 4);
  int*   idx   = (int*)alloc(NHEAD * 32 * 8 * 4);
  float* cb    = (float*)alloc((size_t)NBLK * DIMX * 4);
  us* mixb     = (us*)alloc(SDh);
  float* res   = (float*)alloc(SD);
  us* encb     = (us*)alloc((size_t)L2X * DIMX * 2);
  us* wpack    = (us*)alloc(9 * WSQ);
  us* W1t      = (us*)alloc((size_t)DIMX * FFNX * 2);
  us* W2t      = (us*)alloc((size_t)FFNX * DIMX * 2);
  // aliases (lifetimes disjoint):
  us* ffh     = (us*)qb_;       // SEQ*FFNX bf16 over qb_..vb_
  us* crossb  = mixb;
  us* part4h  = (us*)qb_;       // 4 x SEQ*DIMX bf16 = 25.2MB over qb_+kb_
  us* part4wh = (us*)wpack;     // FFN2 bf16 partials over wpack
  float* outf = (float*)d_out;
  const size_t SL = (size_t)DIMX * DIMX;
  us* Wot  = wpack + 4 * SL;
  us* cWqt = wpack + 5 * SL;
  us* cKVt = wpack + 6 * SL;
  us* cWot = wpack + 8 * SL;

  // ---- pack ----
  P9 p9; p9.s[0]=Wq; p9.s[1]=Wk; p9.s[2]=Wv; p9.s[3]=Wg; p9.s[4]=Wo;
  p9.s[5]=cWq; p9.s[6]=cWk; p9.s[7]=cWv; p9.s[8]=cWo;
  pack64_9<<<dim3(DIMX / 64, DIMX / 64, 9), 256, 0, stream>>>(p9, wpack);
  pack64_g<<<dim3(FFNX / 64, DIMX / 64), 256, 0, stream>>>(W1, W1t, DIMX, FFNX);
  pack64_g<<<dim3(DIMX / 64, FFNX / 64), 256, 0, stream>>>(W2, W2t, FFNX, DIMX);
  pack_cvt_kernel<<<(L2X * DIMX / 4 + 255) / 256, 256, 0, stream>>>(enc, encb, L2X * DIMX / 4);
  prep_e_kernel<<<36, 256, 0, stream>>>(sst, temb, e);

  // ---- self-attention branch ----
  ln_affine_kernel<<<SEQ, 256, 0, stream>>>(hidden, e + DIMX, e, 1, normb);
  Outs qkvgo = {qb_, kb_, vb_, gb_, bq, bk, bv, bg, vbh, gbh};
  gemm2ph<6, 4, 0, 0, 0, 1><<<dim3(8, 32), 512, 0, stream>>>(normb, wpack, qkvgo, SEQ, 4 * DIMX, DIMX, DIMX);
  rms_rope2_kernel<<<dim3(SEQ, 2), 256, 0, stream>>>(qb_, kb_, qnw, knw, cosT, sinT, 1, qbh, kbh);
  block_mean3_kernel<<<dim3(NBLK, NHEAD, 3), 128, 0, stream>>>(qb_, kb_, vb_, qc, kc, vc);
  coarse_attn_kernel<<<NHEAD, 256, 0, stream>>>(qc, kc, pc, idx);
  coarse_ctx_kernel<<<dim3(NBLK, NHEAD), 128, 0, stream>>>(pc, vc, cb);
  attn_kernel<<<dim3(NBLK, NHEAD), 256, 0, stream>>>(qbh, kbh, vbh, idx, gbh, cb, mixb);
  Outs wo_o = {nullptr, nullptr, nullptr, nullptr, nullptr, nullptr, nullptr, nullptr, part4h, nullptr};
  gemm2ph<6, 1, 0, 0, 1, 1><<<dim3(8, 8, 4), 512, 0, stream>>>(mixb, Wot, wo_o, SEQ, DIMX, 384, DIMX);
  reduce_ln_kernel<<<SEQ, 256, 0, stream>>>(part4h, bo, hidden, e + 2 * DIMX,
                                            res, saw, sab, 0, normb);
  // ---- cross attention ----
  gemm2ph<6, 1, 0, 0, 1, 1><<<dim3(8, 8, 4), 512, 0, stream>>>(normb, cWqt, wo_o, SEQ, DIMX, 384, DIMX);
  reduce_rms_kernel<<<SEQ, 256, 0, stream>>>(part4h, cbq, cqnw, qbh);
  Outs ckvo = {kb_, vb_, nullptr, nullptr, cbk, cbv, nullptr, nullptr, vbh, nullptr};
  gemm_multi<2><<<dim3(24, 4), 256, 0, stream>>>(encb, cKVt, ckvo, L2X, 2 * DIMX, DIMX);
  rms_rope_kernel<<<L2X, 256, 0, stream>>>(kb_, cknw, cosT, sinT, 0, kbh);
  attn_kernel<<<dim3(NBLK, NHEAD), 256, 0, stream>>>(qbh, kbh, vbh, nullptr, nullptr, nullptr, crossb);
  gemm2ph<6, 1, 0, 0, 1, 1><<<dim3(8, 8, 4), 512, 0, stream>>>(crossb, cWot, wo_o, SEQ, DIMX, 384, DIMX);
  reduce_ln_kernel<<<SEQ, 256, 0, stream>>>(part4h, cbo, res, nullptr,
                                            outf, e + 4 * DIMX, e + 3 * DIMX, 1, normb);
  // ---- FFN ----
  gemm10<<<dim3(8, 28), 512, 0, stream>>>(normb, W1t, b1, ffh, SEQ, FFNX, DIMX);
  Outs f2o = {nullptr, nullptr, nullptr, nullptr, nullptr, nullptr, nullptr, nullptr, part4wh, nullptr};
  gemm2ph<6, 1, 0, 0, 1, 1><<<dim3(8, 8, 4), 512, 0, stream>>>(ffh, W2t, f2o, SEQ, DIMX, 2240, FFNX);
  reduce4h_kernel<<<1024, 256, 0, stream>>>(part4wh, b2, outf, e + 5 * DIMX, outf,
                                            SEQ * DIMX / 4, DIMX / 4);
}